// Round 8
// baseline (174.429 us; speedup 1.0000x reference)
//
#include <hip/hip_runtime.h>
#include <math.h>

// ---------------- problem constants ----------------
#define NAGT 4096          // BS*NA
#define NE 8
#define NAL 7
#define QTOT (NAGT*14)     // q output elements; hh follows at this offset
#define D_E 4356
#define D_A 4096
#define KPAD 2112          // 33 * 64 K-rows of Wbig

// ---------------- workspace layout (float offsets): weights only ----------------
#define WBIG_OFF 0
#define WBIG_SZ (KPAD*64)                 // 135168
#define WIHT_OFF (WBIG_OFF + WBIG_SZ)
#define WIHT_SZ (64*192)                  // 12288
#define WHHT_OFF (WIHT_OFF + WIHT_SZ)
#define WATT_OFF (WHHT_OFF + WIHT_SZ)
#define WATTB_OFF (WATT_OFF + 4096)
#define BATTT_OFF (WATTB_OFF + 64)
#define BATT0_OFF (BATTT_OFF + 64)

#define PREP_ITEMS (WBIG_SZ + 2*WIHT_SZ + 4096 + 64 + 64 + 1)  // 163969
#define PREP_BLOCKS ((PREP_ITEMS + 255)/256)                   // 641

__device__ __forceinline__ float dot4w(const float* __restrict__ p,
                                       const float* __restrict__ wim, int h) {
    return p[0]*wim[h] + p[1]*wim[64+h] + p[2]*wim[128+h] + p[3]*wim[192+h];
}

// ============================================================
// Kernel 1: weight prep (folds w_in_merge / w_out_merge, GRU transposes)
// Math identical to R1/R2 (PASSED) — only ws offsets moved.
// ============================================================
__global__ __launch_bounds__(256) void k_prep(
    const float* __restrict__ hew2, const float* __restrict__ heb2,
    const float* __restrict__ haw2, const float* __restrict__ hab2,
    const float* __restrict__ wim,  const float* __restrict__ wih,
    const float* __restrict__ whh,  const float* __restrict__ wom,
    const float* __restrict__ fc1w, float* __restrict__ ws)
{
    int idx = blockIdx.x*256 + threadIdx.x;
    if (idx >= PREP_ITEMS) return;
    if (idx < WBIG_SZ) {
        // Wbig rows: [0,1024) Wm_e(f*64+j), [1024,2048) Wm_a,
        // [2048,2064) Bm_e(f), [2064,2080) Bm_a(f), [2080,2096) fc1_w, pad 0
        int rr = idx >> 6, h = idx & 63;
        float s;
        if (rr < 1024) {
            int f = rr >> 6, j = rr & 63;
            s = dot4w(hew2 + (size_t)j*D_E + f*256 + h*4, wim, h);
        } else if (rr < 2048) {
            int r2 = rr - 1024; int f = r2 >> 6, j = r2 & 63;
            s = dot4w(haw2 + (size_t)j*D_A + f*256 + h*4, wim, h);
        } else if (rr < 2064) {
            s = dot4w(heb2 + (rr - 2048)*256 + h*4, wim, h);
        } else if (rr < 2080) {
            s = dot4w(hab2 + (rr - 2064)*256 + h*4, wim, h);
        } else if (rr < 2096) {
            s = fc1w[(rr - 2080)*64 + h];
        } else {
            s = 0.f;
        }
        ws[WBIG_OFF + idx] = s;
        return;
    }
    int k2 = idx - WBIG_SZ;
    if (k2 < WIHT_SZ) {                    // WihT[h*192+c] = wih[c*64+h]
        int h = k2 / 192, c = k2 % 192;
        ws[WIHT_OFF + k2] = wih[c*64 + h];
        return;
    }
    k2 -= WIHT_SZ;
    if (k2 < WIHT_SZ) {
        int h = k2 / 192, c = k2 % 192;
        ws[WHHT_OFF + k2] = whh[c*64 + h];
        return;
    }
    k2 -= WIHT_SZ;
    if (k2 < 4096) {                       // WattT[h*64+j]
        int h = k2 >> 6, j = k2 & 63;
        float s = 0.f;
        #pragma unroll
        for (int k = 0; k < 4; k++)
            s = fmaf(wom[k], hew2[(size_t)j*D_E + 4096 + h*4 + k], s);
        ws[WATT_OFF + k2] = s;
        return;
    }
    k2 -= 4096;
    if (k2 < 64) {                         // wattb[j]
        int j = k2;
        float s = 0.f;
        #pragma unroll
        for (int k = 0; k < 4; k++)
            s = fmaf(wom[k], hew2[(size_t)j*D_E + 4352 + k], s);
        ws[WATTB_OFF + j] = s;
        return;
    }
    k2 -= 64;
    if (k2 < 64) {                         // battT[h]
        int h = k2;
        float s = 0.f;
        #pragma unroll
        for (int k = 0; k < 4; k++)
            s = fmaf(wom[k], heb2[4096 + h*4 + k], s);
        ws[BATTT_OFF + h] = s;
        return;
    }
    {                                      // batt0
        float s = 0.f;
        #pragma unroll
        for (int k = 0; k < 4; k++) s = fmaf(wom[k], heb2[4352 + k], s);
        ws[BATT0_OFF] = s;
    }
}

// ============================================================
// Kernel 2: fully-fused per-block pipeline, 8 agents/block, 4 waves.
// No global intermediates: relu/P/emb all LDS-resident.
// Phase 0 load -> ph1 entity ReLU -> ph2 split-K GEMM (waves own K-rows,
// 8-agent register tile vs L2-resident Wbig) -> reduce -> GRU+heads.
// ============================================================
struct SM {
    float relu_e[8][8][64];    // 16 KB
    float relu_a[8][7][64];    // 14 KB
    float ef_l[8][8][16];      // 4 KB
    float af_l[8][7][16];      // 3.5 KB
    float tails[8][64];        // per-agent K-row 32: [se16|sa16|own16|zero16]
    float pa_lds[4][8][64];    // wave-private PA fragments
    float embp[4][8][64];      // split-K partials; embp[0] reused as lX
    float lH[8][64];
    float lHH[8][64];
    float lU[8][64];
};                             // 62976 B -> 2 blocks/CU

__global__ __launch_bounds__(256) void k_fused(
    const float* __restrict__ own,  const float* __restrict__ ef,
    const float* __restrict__ af,   const float* __restrict__ hidden,
    const float* __restrict__ fc1b, const float* __restrict__ heb1,
    const float* __restrict__ hew1, const float* __restrict__ hab1,
    const float* __restrict__ haw1, const float* __restrict__ gbih,
    const float* __restrict__ gbhh, const float* __restrict__ fc2w,
    const float* __restrict__ fc2b, const float* __restrict__ ws,
    float* __restrict__ out)
{
    __shared__ SM sm;
    int bid = blockIdx.x, t = threadIdx.x;
    int w = t >> 6, l = t & 63;
    int n0 = bid * 8;

    // ---------------- phase 0: stage inputs ----------------
    ((float4*)sm.ef_l)[t] = ((const float4*)(ef + (size_t)n0*128))[t];   // 1024 f
    if (t < 224) ((float4*)sm.af_l)[t] = ((const float4*)(af + (size_t)n0*112))[t];
    if (t < 128) {
        int a = t >> 4, f = t & 15;
        sm.tails[a][32+f] = own[(size_t)n0*16 + t];
        sm.tails[a][48+f] = 0.f;
        ((float4*)sm.lH)[t] = ((const float4*)(hidden + (size_t)n0*64))[t];
    }
    __syncthreads();

    // ---------------- phase 1: entity ReLU rows + feature sums ----------------
    // 120 rows (8 agents x 15 entities); wave w owns rows [w*30, w*30+30)
    for (int i = 0; i < 30; i++) {
        int r = w*30 + i;
        int a = r / 15, ent = r % 15;
        if (ent < 8) {
            float accv = heb1[l];
            #pragma unroll
            for (int f = 0; f < 16; f++)
                accv = fmaf(sm.ef_l[a][ent][f], hew1[f*64 + l], accv);
            sm.relu_e[a][ent][l] = fmaxf(accv, 0.f);
        } else {
            int al = ent - 8;
            float accv = hab1[l];
            #pragma unroll
            for (int f = 0; f < 16; f++)
                accv = fmaf(sm.af_l[a][al][f], haw1[f*64 + l], accv);
            sm.relu_a[a][al][l] = fmaxf(accv, 0.f);
        }
    }
    if (t < 128) {                       // per-feature entity sums
        int a = t >> 4, f = t & 15;
        float se = 0.f, sa = 0.f;
        #pragma unroll
        for (int e = 0; e < 8; e++) se += sm.ef_l[a][e][f];
        #pragma unroll
        for (int e = 0; e < 7; e++) sa += sm.af_l[a][e][f];
        sm.tails[a][f] = se;
        sm.tails[a][16+f] = sa;
    }
    __syncthreads();

    // ---------------- phase 2: split-K GEMM, wave w owns rr = w, w+4, ... ----------------
    // emb[a][h] = sum_k PA[a][k] * Wbig[k][h]; PA recomputed on the fly (8 MAC/elem)
    float acc[8];
    #pragma unroll
    for (int a = 0; a < 8; a++) acc[a] = 0.f;
    const float* Wb = ws + WBIG_OFF;
    for (int rr = w; rr < 33; rr += 4) {
        #pragma unroll 2
        for (int a = 0; a < 8; a++) {    // PA fragment for this K-row block
            float pa;
            if (rr < 16) {
                pa = 0.f;
                #pragma unroll
                for (int e = 0; e < 8; e++)
                    pa = fmaf(sm.ef_l[a][e][rr], sm.relu_e[a][e][l], pa);
            } else if (rr < 32) {
                pa = 0.f;
                #pragma unroll
                for (int e = 0; e < 7; e++)
                    pa = fmaf(sm.af_l[a][e][rr-16], sm.relu_a[a][e][l], pa);
            } else {
                pa = sm.tails[a][l];
            }
            sm.pa_lds[w][a][l] = pa;
            // wave-private buffer; in-wave DS ordering makes this safe
        }
        const float* wbase = Wb + rr*4096 + l;   // lane l = output channel h
        #pragma unroll 4
        for (int k4 = 0; k4 < 16; k4++) {
            float wb0 = wbase[(k4*4+0)*64];
            float wb1 = wbase[(k4*4+1)*64];
            float wb2 = wbase[(k4*4+2)*64];
            float wb3 = wbase[(k4*4+3)*64];
            #pragma unroll
            for (int a = 0; a < 8; a++) {
                float4 pa4 = *(const float4*)&sm.pa_lds[w][a][k4*4];
                acc[a] = fmaf(pa4.x, wb0, acc[a]);
                acc[a] = fmaf(pa4.y, wb1, acc[a]);
                acc[a] = fmaf(pa4.z, wb2, acc[a]);
                acc[a] = fmaf(pa4.w, wb3, acc[a]);
            }
        }
    }
    #pragma unroll
    for (int a = 0; a < 8; a++) sm.embp[w][a][l] = acc[a];
    __syncthreads();

    // ---------------- reduce split-K partials; embp[0] becomes lX ----------------
    #pragma unroll
    for (int ii = 0; ii < 2; ii++) {
        int idx = t + ii*256;
        int a = idx >> 6, h = idx & 63;
        float emb = fc1b[h];
        #pragma unroll
        for (int sw = 0; sw < 4; sw++) emb += sm.embp[sw][a][h];
        sm.embp[0][a][h] = fmaxf(emb, 0.f);
    }
    __syncthreads();

    // ---------------- phase 3: GRU + Q heads (wave w -> agents 2w, 2w+1) ----------------
    {
        int a0 = w*2;
        float hid[2], gir[2], giz[2], gig[2], ghr[2], ghz[2], ghg[2];
        #pragma unroll
        for (int q = 0; q < 2; q++) {
            hid[q] = sm.lH[a0+q][l];
            gir[q] = gbih[l]; giz[q] = gbih[64+l]; gig[q] = gbih[128+l];
            ghr[q] = gbhh[l]; ghz[q] = gbhh[64+l]; ghg[q] = gbhh[128+l];
        }
        const float* WihT = ws + WIHT_OFF;
        const float* WhhT = ws + WHHT_OFF;
        #pragma unroll 8
        for (int h = 0; h < 64; h++) {
            float wri = WihT[h*192 + l], wzi = WihT[h*192 + 64 + l], wgi = WihT[h*192 + 128 + l];
            float wrh = WhhT[h*192 + l], wzh = WhhT[h*192 + 64 + l], wgh = WhhT[h*192 + 128 + l];
            #pragma unroll
            for (int q = 0; q < 2; q++) {
                float xv = sm.embp[0][a0+q][h], hv = sm.lH[a0+q][h];
                gir[q] = fmaf(xv, wri, gir[q]); giz[q] = fmaf(xv, wzi, giz[q]);
                gig[q] = fmaf(xv, wgi, gig[q]);
                ghr[q] = fmaf(hv, wrh, ghr[q]); ghz[q] = fmaf(hv, wzh, ghz[q]);
                ghg[q] = fmaf(hv, wgh, ghg[q]);
            }
        }
        #pragma unroll
        for (int q = 0; q < 2; q++) {
            float r = 1.f/(1.f + expf(-(gir[q] + ghr[q])));
            float z = 1.f/(1.f + expf(-(giz[q] + ghz[q])));
            float g = tanhf(gig[q] + r*ghg[q]);
            float hv = (1.f - z)*g + z*hid[q];
            sm.lHH[a0+q][l] = hv;
            out[QTOT + (size_t)(n0 + a0 + q)*64 + l] = hv;
        }

        // u[n,j] = wattb[j] + sum_h hh*WattT[h,j];  cb = batt0 + sum_h hh*battT[h]
        const float* WattT = ws + WATT_OFF;
        float b0 = ws[BATT0_OFF];
        float u[2], cb[2];
        #pragma unroll
        for (int q = 0; q < 2; q++) { u[q] = ws[WATTB_OFF + l]; cb[q] = b0; }
        #pragma unroll 8
        for (int h = 0; h < 64; h++) {
            float wa = WattT[h*64 + l];
            float bt = ws[BATTT_OFF + h];
            #pragma unroll
            for (int q = 0; q < 2; q++) {
                float hv = sm.lHH[a0+q][h];
                u[q]  = fmaf(hv, wa, u[q]);
                cb[q] = fmaf(hv, bt, cb[q]);
            }
        }
        #pragma unroll
        for (int q = 0; q < 2; q++) sm.lU[a0+q][l] = u[q];

        // q_attack[n,e] = sum_j relu_e[n,e,j]*u[n,j] + cb ; lanes = (e,p) 8x8
        int e = l >> 3, p = l & 7;
        #pragma unroll
        for (int q = 0; q < 2; q++) {
            int a = a0 + q, n = n0 + a;
            float4 r0 = *(const float4*)&sm.relu_e[a][e][p*8];
            float4 r1 = *(const float4*)&sm.relu_e[a][e][p*8 + 4];
            float s = 0.f;
            s = fmaf(r0.x, sm.lU[a][p*8 + 0], s); s = fmaf(r0.y, sm.lU[a][p*8 + 1], s);
            s = fmaf(r0.z, sm.lU[a][p*8 + 2], s); s = fmaf(r0.w, sm.lU[a][p*8 + 3], s);
            s = fmaf(r1.x, sm.lU[a][p*8 + 4], s); s = fmaf(r1.y, sm.lU[a][p*8 + 5], s);
            s = fmaf(r1.z, sm.lU[a][p*8 + 6], s); s = fmaf(r1.w, sm.lU[a][p*8 + 7], s);
            s += __shfl_xor(s, 1); s += __shfl_xor(s, 2); s += __shfl_xor(s, 4);
            if (p == 0) out[(size_t)n*14 + 6 + e] = s + cb[q];
        }
        // q_normal: 12 lanes cover (q,o)
        if (l < 12) {
            int q = l / 6, o = l % 6;
            float qn = fc2b[o];
            #pragma unroll 8
            for (int h = 0; h < 64; h++) qn = fmaf(sm.lHH[a0+q][h], fc2w[h*6 + o], qn);
            out[(size_t)(n0 + a0 + q)*14 + o] = qn;
        }
    }
}

// ============================================================
extern "C" void kernel_launch(void* const* d_in, const int* in_sizes, int n_in,
                              void* d_out, int out_size, void* d_ws, size_t ws_size,
                              hipStream_t stream) {
    const float* own   = (const float*)d_in[0];
    const float* ef    = (const float*)d_in[1];
    const float* af    = (const float*)d_in[2];
    const float* hidden= (const float*)d_in[3];
    const float* fc1w  = (const float*)d_in[4];
    const float* fc1b  = (const float*)d_in[5];
    const float* hew1  = (const float*)d_in[6];
    const float* heb1  = (const float*)d_in[7];
    const float* hew2  = (const float*)d_in[8];
    const float* heb2  = (const float*)d_in[9];
    const float* haw1  = (const float*)d_in[10];
    const float* hab1  = (const float*)d_in[11];
    const float* haw2  = (const float*)d_in[12];
    const float* hab2  = (const float*)d_in[13];
    const float* wim   = (const float*)d_in[14];
    const float* wih   = (const float*)d_in[15];
    const float* gbih  = (const float*)d_in[16];
    const float* whh   = (const float*)d_in[17];
    const float* gbhh  = (const float*)d_in[18];
    const float* fc2w  = (const float*)d_in[19];
    const float* fc2b  = (const float*)d_in[20];
    const float* wom   = (const float*)d_in[21];
    float* out = (float*)d_out;
    float* ws  = (float*)d_ws;

    k_prep<<<PREP_BLOCKS, 256, 0, stream>>>(hew2, heb2, haw2, hab2, wim,
                                            wih, whh, wom, fc1w, ws);
    k_fused<<<NAGT/8, 256, 0, stream>>>(own, ef, af, hidden, fc1b, heb1,
                                        hew1, hab1, haw1, gbih, gbhh,
                                        fc2w, fc2b, ws, out);
}

// Round 10
// 145.428 us; speedup vs baseline: 1.1994x; 1.1994x over previous
//
#include <hip/hip_runtime.h>
#include <math.h>

// ---------------- problem constants ----------------
#define NAGT 4096          // BS*NA
#define NE 8
#define NAL 7
#define QTOT (NAGT*14)     // q output elements; hh follows at this offset
#define D_E 4356
#define D_A 4096
#define KPAD 2112          // 33 * 64 K-rows of Wbig

// ---------------- workspace layout (float offsets): weights only ----------------
#define WBIG_OFF 0
#define WBIG_SZ (KPAD*64)                 // 135168
#define WIHT_OFF (WBIG_OFF + WBIG_SZ)
#define WIHT_SZ (64*192)                  // 12288
#define WHHT_OFF (WIHT_OFF + WIHT_SZ)
#define WATT_OFF (WHHT_OFF + WIHT_SZ)
#define WATTB_OFF (WATT_OFF + 4096)
#define BATTT_OFF (WATTB_OFF + 64)
#define BATT0_OFF (BATTT_OFF + 64)

#define PREP_ITEMS (WBIG_SZ + 2*WIHT_SZ + 4096 + 64 + 64 + 1)  // 163969
#define PREP_BLOCKS ((PREP_ITEMS + 255)/256)                   // 641

__device__ __forceinline__ float dot4w(const float* __restrict__ p,
                                       const float* __restrict__ wim, int h) {
    return p[0]*wim[h] + p[1]*wim[64+h] + p[2]*wim[128+h] + p[3]*wim[192+h];
}

// ============================================================
// Kernel 1: weight prep (folds w_in_merge / w_out_merge, GRU transposes)
// Unchanged from R8 (PASSED).
// ============================================================
__global__ __launch_bounds__(256) void k_prep(
    const float* __restrict__ hew2, const float* __restrict__ heb2,
    const float* __restrict__ haw2, const float* __restrict__ hab2,
    const float* __restrict__ wim,  const float* __restrict__ wih,
    const float* __restrict__ whh,  const float* __restrict__ wom,
    const float* __restrict__ fc1w, float* __restrict__ ws)
{
    int idx = blockIdx.x*256 + threadIdx.x;
    if (idx >= PREP_ITEMS) return;
    if (idx < WBIG_SZ) {
        int rr = idx >> 6, h = idx & 63;
        float s;
        if (rr < 1024) {
            int f = rr >> 6, j = rr & 63;
            s = dot4w(hew2 + (size_t)j*D_E + f*256 + h*4, wim, h);
        } else if (rr < 2048) {
            int r2 = rr - 1024; int f = r2 >> 6, j = r2 & 63;
            s = dot4w(haw2 + (size_t)j*D_A + f*256 + h*4, wim, h);
        } else if (rr < 2064) {
            s = dot4w(heb2 + (rr - 2048)*256 + h*4, wim, h);
        } else if (rr < 2080) {
            s = dot4w(hab2 + (rr - 2064)*256 + h*4, wim, h);
        } else if (rr < 2096) {
            s = fc1w[(rr - 2080)*64 + h];
        } else {
            s = 0.f;
        }
        ws[WBIG_OFF + idx] = s;
        return;
    }
    int k2 = idx - WBIG_SZ;
    if (k2 < WIHT_SZ) {                    // WihT[h*192+c] = wih[c*64+h]
        int h = k2 / 192, c = k2 % 192;
        ws[WIHT_OFF + k2] = wih[c*64 + h];
        return;
    }
    k2 -= WIHT_SZ;
    if (k2 < WIHT_SZ) {
        int h = k2 / 192, c = k2 % 192;
        ws[WHHT_OFF + k2] = whh[c*64 + h];
        return;
    }
    k2 -= WIHT_SZ;
    if (k2 < 4096) {                       // WattT[h*64+j]
        int h = k2 >> 6, j = k2 & 63;
        float s = 0.f;
        #pragma unroll
        for (int k = 0; k < 4; k++)
            s = fmaf(wom[k], hew2[(size_t)j*D_E + 4096 + h*4 + k], s);
        ws[WATT_OFF + k2] = s;
        return;
    }
    k2 -= 4096;
    if (k2 < 64) {                         // wattb[j]
        int j = k2;
        float s = 0.f;
        #pragma unroll
        for (int k = 0; k < 4; k++)
            s = fmaf(wom[k], hew2[(size_t)j*D_E + 4352 + k], s);
        ws[WATTB_OFF + j] = s;
        return;
    }
    k2 -= 64;
    if (k2 < 64) {                         // battT[h]
        int h = k2;
        float s = 0.f;
        #pragma unroll
        for (int k = 0; k < 4; k++)
            s = fmaf(wom[k], heb2[4096 + h*4 + k], s);
        ws[BATTT_OFF + h] = s;
        return;
    }
    {                                      // batt0
        float s = 0.f;
        #pragma unroll
        for (int k = 0; k < 4; k++) s = fmaf(wom[k], heb2[4352 + k], s);
        ws[BATT0_OFF] = s;
    }
}

// ============================================================
// Kernel 2: fused pipeline, 8 agents/block, 8 waves (512 thr).
// Phase 2 uses a 4-h-per-lane register tile: lane (kg=l>>4, hp=l&15)
// owns h=4hp..4hp+3 over k-subrange kg*16..+15 -> each pa4 LDS read
// feeds 16 FMAs (vs 4 in R8); W loads are float4.
// ============================================================
struct SMT {
    float relu_e[8][8][64];    // 16 KB (live ph1-3: attack-Q reads it)
    union {
        float relu_a[8][7][64];                         // 14 KB, ph1-2
        struct { float lHH[8][64]; float lU[8][64]; } ep;  // 4 KB, ph3
    } u;
    float ef_l[8][8][16];      // 4 KB
    float af_l[8][7][16];      // 3.5 KB
    float tails[8][64];        // 2 KB   K-row 32: [se16|sa16|own16|0]
    float pamem[8][8][64];     // 16 KB  per-wave pa; then partials; [0]=lX
    float lH[8][64];           // 2 KB
};                             // 58,880 B -> 2 blocks/CU at 512 thr

__global__ __launch_bounds__(512, 4) void k_fused(
    const float* __restrict__ own,  const float* __restrict__ ef,
    const float* __restrict__ af,   const float* __restrict__ hidden,
    const float* __restrict__ fc1b, const float* __restrict__ heb1,
    const float* __restrict__ hew1, const float* __restrict__ hab1,
    const float* __restrict__ haw1, const float* __restrict__ gbih,
    const float* __restrict__ gbhh, const float* __restrict__ fc2w,
    const float* __restrict__ fc2b, const float* __restrict__ ws,
    float* __restrict__ out)
{
    __shared__ SMT sm;
    int bid = blockIdx.x, t = threadIdx.x;
    int w = t >> 6, l = t & 63;
    int n0 = bid * 8;

    // ---------------- phase 0: stage inputs ----------------
    if (t < 256) ((float4*)sm.ef_l)[t] = ((const float4*)(ef + (size_t)n0*128))[t];
    if (t < 224) ((float4*)sm.af_l)[t] = ((const float4*)(af + (size_t)n0*112))[t];
    if (t < 128) {
        int a = t >> 4, f = t & 15;
        sm.tails[a][32+f] = own[(size_t)n0*16 + t];
        sm.tails[a][48+f] = 0.f;
        ((float4*)sm.lH)[t] = ((const float4*)(hidden + (size_t)n0*64))[t];
    }
    __syncthreads();

    // ---------------- phase 1: entity ReLU rows (wave w = agent w) ----------------
    for (int ent = 0; ent < 15; ent++) {
        if (ent < 8) {
            float accv = heb1[l];
            #pragma unroll
            for (int f = 0; f < 16; f++)
                accv = fmaf(sm.ef_l[w][ent][f], hew1[f*64 + l], accv);
            sm.relu_e[w][ent][l] = fmaxf(accv, 0.f);
        } else {
            int al = ent - 8;
            float accv = hab1[l];
            #pragma unroll
            for (int f = 0; f < 16; f++)
                accv = fmaf(sm.af_l[w][al][f], haw1[f*64 + l], accv);
            sm.u.relu_a[w][al][l] = fmaxf(accv, 0.f);
        }
    }
    if (t < 128) {                       // per-feature entity sums
        int a = t >> 4, f = t & 15;
        float se = 0.f, sa = 0.f;
        #pragma unroll
        for (int e = 0; e < 8; e++) se += sm.ef_l[a][e][f];
        #pragma unroll
        for (int e = 0; e < 7; e++) sa += sm.af_l[a][e][f];
        sm.tails[a][f] = se;
        sm.tails[a][16+f] = sa;
    }
    __syncthreads();

    // ---------------- phase 2: split-K GEMM, wave w owns rr = w, w+8, ... ----------------
    // emb[a][h] = sum_k PA[a][k]*Wbig[k][h]; lane tile = 8 agents x 4 h.
    int kg = l >> 4, hp = l & 15;
    float acc[8][4];
    #pragma unroll
    for (int a = 0; a < 8; a++)
        #pragma unroll
        for (int c = 0; c < 4; c++) acc[a][c] = 0.f;
    const float* Wb = ws + WBIG_OFF;

    for (int rr = w; rr < 33; rr += 8) {
        // PA for k=l, all 8 agents (write one k-slot each)
        #pragma unroll
        for (int a = 0; a < 8; a++) {
            float pa;
            if (rr < 16) {
                pa = 0.f;
                #pragma unroll
                for (int e = 0; e < 8; e++)
                    pa = fmaf(sm.ef_l[a][e][rr], sm.relu_e[a][e][l], pa);
            } else if (rr < 32) {
                pa = 0.f;
                #pragma unroll
                for (int e = 0; e < 7; e++)
                    pa = fmaf(sm.af_l[a][e][rr-16], sm.u.relu_a[a][e][l], pa);
            } else {
                pa = sm.tails[a][l];
            }
            sm.pamem[w][a][l] = pa;   // in-wave DS ordering: write-then-read safe
        }
        const float* wbase = Wb + rr*4096 + kg*1024 + hp*4;
        #pragma unroll
        for (int kk4 = 0; kk4 < 4; kk4++) {
            float4 pa4[8];
            #pragma unroll
            for (int a = 0; a < 8; a++)
                pa4[a] = *(const float4*)&sm.pamem[w][a][kg*16 + kk4*4];
            #pragma unroll
            for (int uu = 0; uu < 4; uu++) {
                float4 wv = *(const float4*)(wbase + (kk4*4 + uu)*64);
                #pragma unroll
                for (int a = 0; a < 8; a++) {
                    float p = (uu==0) ? pa4[a].x : (uu==1) ? pa4[a].y
                             : (uu==2) ? pa4[a].z : pa4[a].w;
                    acc[a][0] = fmaf(p, wv.x, acc[a][0]);
                    acc[a][1] = fmaf(p, wv.y, acc[a][1]);
                    acc[a][2] = fmaf(p, wv.z, acc[a][2]);
                    acc[a][3] = fmaf(p, wv.w, acc[a][3]);
                }
            }
        }
    }
    // cross-kg reduce (lanes l, l^16, l^32, l^48 share the same 4 h-columns)
    #pragma unroll
    for (int a = 0; a < 8; a++) {
        float v0 = acc[a][0], v1 = acc[a][1], v2 = acc[a][2], v3 = acc[a][3];
        v0 += __shfl_xor(v0, 16); v0 += __shfl_xor(v0, 32);
        v1 += __shfl_xor(v1, 16); v1 += __shfl_xor(v1, 32);
        v2 += __shfl_xor(v2, 16); v2 += __shfl_xor(v2, 32);
        v3 += __shfl_xor(v3, 16); v3 += __shfl_xor(v3, 32);
        float vv = (kg==0) ? v0 : (kg==1) ? v1 : (kg==2) ? v2 : v3;
        sm.pamem[w][a][4*hp + kg] = vv;   // wave-partial emb, h = 4hp+kg
    }
    __syncthreads();

    // ---------------- reduce 8 wave-partials; pamem[0] becomes lX ----------------
    {
        int a = t >> 6, h = t & 63;      // 512 threads = all (a,h)
        float emb = fc1b[h];
        #pragma unroll
        for (int sw = 0; sw < 8; sw++) emb += sm.pamem[sw][a][h];
        sm.pamem[0][a][h] = fmaxf(emb, 0.f);
    }
    __syncthreads();

    // ---------------- phase 3: GRU + Q heads (waves 0-3, 2 agents each) ----------------
    if (w < 4) {
        int a0 = w*2;
        float hid[2], gir[2], giz[2], gig[2], ghr[2], ghz[2], ghg[2];
        #pragma unroll
        for (int q = 0; q < 2; q++) {
            hid[q] = sm.lH[a0+q][l];
            gir[q] = gbih[l]; giz[q] = gbih[64+l]; gig[q] = gbih[128+l];
            ghr[q] = gbhh[l]; ghz[q] = gbhh[64+l]; ghg[q] = gbhh[128+l];
        }
        const float* WihT = ws + WIHT_OFF;
        const float* WhhT = ws + WHHT_OFF;
        #pragma unroll 8
        for (int h = 0; h < 64; h++) {
            float wri = WihT[h*192 + l], wzi = WihT[h*192 + 64 + l], wgi = WihT[h*192 + 128 + l];
            float wrh = WhhT[h*192 + l], wzh = WhhT[h*192 + 64 + l], wgh = WhhT[h*192 + 128 + l];
            #pragma unroll
            for (int q = 0; q < 2; q++) {
                float xv = sm.pamem[0][a0+q][h], hv = sm.lH[a0+q][h];
                gir[q] = fmaf(xv, wri, gir[q]); giz[q] = fmaf(xv, wzi, giz[q]);
                gig[q] = fmaf(xv, wgi, gig[q]);
                ghr[q] = fmaf(hv, wrh, ghr[q]); ghz[q] = fmaf(hv, wzh, ghz[q]);
                ghg[q] = fmaf(hv, wgh, ghg[q]);
            }
        }
        #pragma unroll
        for (int q = 0; q < 2; q++) {
            float r = 1.f/(1.f + expf(-(gir[q] + ghr[q])));
            float z = 1.f/(1.f + expf(-(giz[q] + ghz[q])));
            float g = tanhf(gig[q] + r*ghg[q]);
            float hv = (1.f - z)*g + z*hid[q];
            sm.u.ep.lHH[a0+q][l] = hv;
            out[QTOT + (size_t)(n0 + a0 + q)*64 + l] = hv;
        }

        // u[n,j] = wattb[j] + sum_h hh*WattT[h,j];  cb = batt0 + sum_h hh*battT[h]
        const float* WattT = ws + WATT_OFF;
        float b0 = ws[BATT0_OFF];
        float uacc[2], cb[2];
        #pragma unroll
        for (int q = 0; q < 2; q++) { uacc[q] = ws[WATTB_OFF + l]; cb[q] = b0; }
        #pragma unroll 8
        for (int h = 0; h < 64; h++) {
            float wa = WattT[h*64 + l];
            float bt = ws[BATTT_OFF + h];
            #pragma unroll
            for (int q = 0; q < 2; q++) {
                float hv = sm.u.ep.lHH[a0+q][h];
                uacc[q] = fmaf(hv, wa, uacc[q]);
                cb[q]   = fmaf(hv, bt, cb[q]);
            }
        }
        #pragma unroll
        for (int q = 0; q < 2; q++) sm.u.ep.lU[a0+q][l] = uacc[q];

        // q_attack[n,e] = sum_j relu_e[n,e,j]*u[n,j] + cb ; lanes = (e,p) 8x8
        int e = l >> 3, p = l & 7;
        #pragma unroll
        for (int q = 0; q < 2; q++) {
            int a = a0 + q, n = n0 + a;
            float4 r0 = *(const float4*)&sm.relu_e[a][e][p*8];
            float4 r1 = *(const float4*)&sm.relu_e[a][e][p*8 + 4];
            float s = 0.f;
            s = fmaf(r0.x, sm.u.ep.lU[a][p*8 + 0], s); s = fmaf(r0.y, sm.u.ep.lU[a][p*8 + 1], s);
            s = fmaf(r0.z, sm.u.ep.lU[a][p*8 + 2], s); s = fmaf(r0.w, sm.u.ep.lU[a][p*8 + 3], s);
            s = fmaf(r1.x, sm.u.ep.lU[a][p*8 + 4], s); s = fmaf(r1.y, sm.u.ep.lU[a][p*8 + 5], s);
            s = fmaf(r1.z, sm.u.ep.lU[a][p*8 + 6], s); s = fmaf(r1.w, sm.u.ep.lU[a][p*8 + 7], s);
            s += __shfl_xor(s, 1); s += __shfl_xor(s, 2); s += __shfl_xor(s, 4);
            if (p == 0) out[(size_t)n*14 + 6 + e] = s + cb[q];
        }
        // q_normal: 12 lanes cover (q,o)
        if (l < 12) {
            int q = l / 6, o = l % 6;
            float qn = fc2b[o];
            #pragma unroll 8
            for (int h = 0; h < 64; h++) qn = fmaf(sm.u.ep.lHH[a0+q][h], fc2w[h*6 + o], qn);
            out[(size_t)(n0 + a0 + q)*14 + o] = qn;
        }
    }
}

// ============================================================
extern "C" void kernel_launch(void* const* d_in, const int* in_sizes, int n_in,
                              void* d_out, int out_size, void* d_ws, size_t ws_size,
                              hipStream_t stream) {
    const float* own   = (const float*)d_in[0];
    const float* ef    = (const float*)d_in[1];
    const float* af    = (const float*)d_in[2];
    const float* hidden= (const float*)d_in[3];
    const float* fc1w  = (const float*)d_in[4];
    const float* fc1b  = (const float*)d_in[5];
    const float* hew1  = (const float*)d_in[6];
    const float* heb1  = (const float*)d_in[7];
    const float* hew2  = (const float*)d_in[8];
    const float* heb2  = (const float*)d_in[9];
    const float* haw1  = (const float*)d_in[10];
    const float* hab1  = (const float*)d_in[11];
    const float* haw2  = (const float*)d_in[12];
    const float* hab2  = (const float*)d_in[13];
    const float* wim   = (const float*)d_in[14];
    const float* wih   = (const float*)d_in[15];
    const float* gbih  = (const float*)d_in[16];
    const float* whh   = (const float*)d_in[17];
    const float* gbhh  = (const float*)d_in[18];
    const float* fc2w  = (const float*)d_in[19];
    const float* fc2b  = (const float*)d_in[20];
    const float* wom   = (const float*)d_in[21];
    float* out = (float*)d_out;
    float* ws  = (float*)d_ws;

    k_prep<<<PREP_BLOCKS, 256, 0, stream>>>(hew2, heb2, haw2, hab2, wim,
                                            wih, whh, wom, fc1w, ws);
    k_fused<<<NAGT/8, 512, 0, stream>>>(own, ef, af, hidden, fc1b, heb1,
                                        hew1, hab1, haw1, gbih, gbhh,
                                        fc2w, fc2b, ws, out);
}